// Round 5
// baseline (406.713 us; speedup 1.0000x reference)
//
#include <hip/hip_runtime.h>

#define N_NODES 50000
#define N_EDGES 800000
#define SCAN_NB ((N_NODES + 255) / 256)   // 196
#define NCHUNK 32
#define NRANGE 4
#define RNODES (N_NODES / NRANGE)         // 12500
#define CEDGES (N_EDGES / NCHUNK)         // 25000

typedef __attribute__((ext_vector_type(8))) short short8;
typedef __attribute__((ext_vector_type(4))) float f32x4;

__device__ inline unsigned short f2b(float f) {
    union { float f; unsigned u; } c; c.f = f;
    return (unsigned short)((c.u + 0x7FFFu + ((c.u >> 16) & 1u)) >> 16);
}
__device__ inline float b2f(unsigned short h) {
    union { unsigned u; float f; } c; c.u = ((unsigned)h) << 16;
    return c.f;
}

// ---------------------------------------------------------------------------
// K1: partial histograms. Block = (chunk, range). LDS atomics only.
__global__ __launch_bounds__(256) void histp_kernel(const int* __restrict__ dst,
                                                    int* __restrict__ hist_part) {
    __shared__ int h[RNODES];
    const int chunk = blockIdx.x >> 2;
    const int range = blockIdx.x & 3;
    const int nbase = range * RNODES;
    for (int i = threadIdx.x; i < RNODES; i += 256) h[i] = 0;
    __syncthreads();
    const int* dp = dst + chunk * CEDGES;
    for (int i = threadIdx.x; i < CEDGES; i += 256) {
        int d = dp[i] - nbase;
        if ((unsigned)d < (unsigned)RNODES) atomicAdd(&h[d], 1);
    }
    __syncthreads();
    int* out = hist_part + chunk * N_NODES + nbase;
    for (int i = threadIdx.x; i < RNODES; i += 256) out[i] = h[i];
}

// ---------------------------------------------------------------------------
// K2: per node, exclusive scan across chunks (in place) + total count.
__global__ __launch_bounds__(256) void chunkscan_kernel(int* __restrict__ hist_part,
                                                        int* __restrict__ cnt) {
    int node = blockIdx.x * 256 + threadIdx.x;
    if (node >= N_NODES) return;
    int run = 0;
    #pragma unroll
    for (int c = 0; c < NCHUNK; ++c) {
        int* p = hist_part + c * N_NODES + node;
        int v = *p;
        *p = run;
        run += v;
    }
    cnt[node] = run;
}

// ---------------------------------------------------------------------------
// Hierarchical scan of cnt -> off (exclusive), off[N] = total.
__global__ __launch_bounds__(256) void scanA_kernel(const int* __restrict__ cnt,
                                                    int* __restrict__ off,
                                                    int* __restrict__ bsum) {
    __shared__ int tmp[256];
    const int t = threadIdx.x;
    const int i = blockIdx.x * 256 + t;
    int v = (i < N_NODES) ? cnt[i] : 0;
    tmp[t] = v;
    __syncthreads();
    #pragma unroll
    for (int d = 1; d < 256; d <<= 1) {
        int u = (t >= d) ? tmp[t - d] : 0;
        __syncthreads();
        tmp[t] += u;
        __syncthreads();
    }
    if (i < N_NODES) off[i] = tmp[t] - v;
    if (t == 255) bsum[blockIdx.x] = tmp[255];
}

__global__ __launch_bounds__(256) void scanB_kernel(const int* __restrict__ bsum,
                                                    int* __restrict__ boff,
                                                    int* __restrict__ off) {
    __shared__ int tmp[256];
    const int t = threadIdx.x;
    int v = (t < SCAN_NB) ? bsum[t] : 0;
    tmp[t] = v;
    __syncthreads();
    #pragma unroll
    for (int d = 1; d < 256; d <<= 1) {
        int u = (t >= d) ? tmp[t - d] : 0;
        __syncthreads();
        tmp[t] += u;
        __syncthreads();
    }
    if (t < SCAN_NB) boff[t] = tmp[t] - v;
    if (t == 255) off[N_NODES] = tmp[255];
}

__global__ __launch_bounds__(256) void scanC_kernel(const int* __restrict__ boff,
                                                    int* __restrict__ off) {
    int i = blockIdx.x * 256 + threadIdx.x;
    if (i < N_NODES) off[i] += boff[blockIdx.x];
}

// ---------------------------------------------------------------------------
// K3: fill csr. Cursor = off[d] + base[chunk][d] held in LDS; LDS atomics rank
// edges; plain global stores only.
__global__ __launch_bounds__(256) void fillp_kernel(const int* __restrict__ src,
                                                    const int* __restrict__ dst,
                                                    const int* __restrict__ off,
                                                    const int* __restrict__ hist_part,
                                                    int* __restrict__ csr) {
    __shared__ int cur[RNODES];
    const int chunk = blockIdx.x >> 2;
    const int range = blockIdx.x & 3;
    const int nbase = range * RNODES;
    const int* bp = hist_part + chunk * N_NODES + nbase;
    const int* op = off + nbase;
    for (int i = threadIdx.x; i < RNODES; i += 256) cur[i] = op[i] + bp[i];
    __syncthreads();
    const int* dp = dst + chunk * CEDGES;
    const int* sp = src + chunk * CEDGES;
    for (int i = threadIdx.x; i < CEDGES; i += 256) {
        int d = dp[i] - nbase;
        if ((unsigned)d < (unsigned)RNODES) {
            int pos = atomicAdd(&cur[d], 1);
            csr[pos] = sp[i];
        }
    }
}

// ---------------------------------------------------------------------------
// x (fp32) -> bf16
__global__ __launch_bounds__(256) void convert_x_kernel(const float* __restrict__ x,
                                                        unsigned short* __restrict__ xb) {
    long i = ((long)blockIdx.x * 256 + threadIdx.x) * 4;
    if (i < (long)N_NODES * 64) {
        float4 v = *(const float4*)(x + i);
        ushort4 o;
        o.x = f2b(v.x); o.y = f2b(v.y); o.z = f2b(v.z); o.w = f2b(v.w);
        *(ushort4*)(xb + i) = o;
    }
}

// ---------------------------------------------------------------------------
// Pack one layer's weights into B-fragment order (bf16).
__global__ __launch_bounds__(256) void pack_w_kernel(
    const float* __restrict__ W1, const float* __restrict__ W2,
    const float* __restrict__ W3, const float* __restrict__ Wl,
    unsigned short* __restrict__ Wp)
{
    for (int idx = threadIdx.x; idx < 16 * 2 * 64 * 8; idx += 256) {
        int j = idx & 7, lane = (idx >> 3) & 63, s = (idx >> 9) & 1, ct = idx >> 10;
        int k = s * 32 + (lane >> 4) * 8 + j;
        int col = ct * 16 + (lane & 15);
        float v;
        if (ct < 4)       v = W1[k * 64 + col];
        else if (ct < 8)  v = W2[k * 64 + col - 64];
        else if (ct < 12) v = W3[k * 64 + col - 128];
        else              v = Wl[k * 64 + col - 192];
        Wp[idx] = f2b(v);
    }
}

// ---------------------------------------------------------------------------
// [a|b|c] = h @ [W1|W2|W3] + [b1|0|b3], bf16 MFMA, no LDS.
__global__ __launch_bounds__(256) void gemm3_mfma_kernel(
    const unsigned short* __restrict__ hbf,
    const unsigned short* __restrict__ Wp,
    const float* __restrict__ b1, const float* __restrict__ b3,
    unsigned short* __restrict__ abf, unsigned short* __restrict__ bbf,
    unsigned short* __restrict__ cbf, int n)
{
    const int t = threadIdx.x;
    const int lane = t & 63;
    const int quad = lane >> 4, lm = lane & 15;
    const int row_base = blockIdx.x * 64 + (t >> 6) * 16;

    int arow = min(row_base + lm, n - 1);
    const unsigned short* hrow = hbf + (long)arow * 64;
    short8 a0 = *(const short8*)(hrow + quad * 8);
    short8 a1 = *(const short8*)(hrow + 32 + quad * 8);

    const short8* wp = (const short8*)Wp;
    f32x4 acc[12];
    #pragma unroll
    for (int ct = 0; ct < 12; ++ct) {
        f32x4 z = {0.f, 0.f, 0.f, 0.f};
        short8 w0 = wp[(ct * 2 + 0) * 64 + lane];
        short8 w1 = wp[(ct * 2 + 1) * 64 + lane];
        z = __builtin_amdgcn_mfma_f32_16x16x32_bf16(a0, w0, z, 0, 0, 0);
        z = __builtin_amdgcn_mfma_f32_16x16x32_bf16(a1, w1, z, 0, 0, 0);
        acc[ct] = z;
    }

    #pragma unroll
    for (int ct = 0; ct < 12; ++ct) {
        int col = ct * 16 + lm;
        float bias = 0.f;
        unsigned short* dstp;
        int lcol;
        if (ct < 4)       { bias = b1[col];        dstp = abf; lcol = col; }
        else if (ct < 8)  {                        dstp = bbf; lcol = col - 64; }
        else              { bias = b3[col - 128];  dstp = cbf; lcol = col - 128; }
        #pragma unroll
        for (int r = 0; r < 4; ++r) {
            int g = row_base + quad * 4 + r;
            if (g < n) dstp[(long)g * 64 + lcol] = f2b(acc[ct][r] + bias);
        }
    }
}

// ---------------------------------------------------------------------------
// CSR gather over bf16 a-rows.
__global__ __launch_bounds__(256) void gather_kernel(
    const int* __restrict__ off, const int* __restrict__ csr,
    const unsigned short* __restrict__ abf, float* __restrict__ S, int n)
{
    int node = blockIdx.x * 4 + (threadIdx.x >> 6);
    int lane = threadIdx.x & 63;
    if (node >= n) return;
    int beg = off[node], end = off[node + 1];
    float acc = 0.0f;
    int j = beg;
    for (; j + 3 < end; j += 4) {
        int s0 = csr[j], s1 = csr[j + 1], s2 = csr[j + 2], s3 = csr[j + 3];
        float v0 = b2f(abf[(long)s0 * 64 + lane]);
        float v1 = b2f(abf[(long)s1 * 64 + lane]);
        float v2 = b2f(abf[(long)s2 * 64 + lane]);
        float v3 = b2f(abf[(long)s3 * 64 + lane]);
        acc += v0 + v1 + v2 + v3;
    }
    for (; j < end; ++j) acc += b2f(abf[(long)csr[j] * 64 + lane]);
    S[(long)node * 64 + lane] = acc;
}

// ---------------------------------------------------------------------------
// out = relu( (S - deg*b + c) @ Wl + bl )
__global__ __launch_bounds__(256) void combine_mfma_kernel(
    const float* __restrict__ S, const unsigned short* __restrict__ bbf,
    const unsigned short* __restrict__ cbf, const int* __restrict__ off,
    const unsigned short* __restrict__ Wp, const float* __restrict__ bl,
    float* __restrict__ out_f, unsigned short* __restrict__ out_b,
    int n, int last)
{
    const int t = threadIdx.x;
    const int lane = t & 63;
    const int quad = lane >> 4, lm = lane & 15;
    const int row_base = blockIdx.x * 64 + (t >> 6) * 16;

    int prow = min(row_base + lm, n - 1);
    float deg = (float)(off[prow + 1] - off[prow]);

    short8 p[2];
    #pragma unroll
    for (int s = 0; s < 2; ++s) {
        int k0 = s * 32 + quad * 8;
        const float* sp = S + (long)prow * 64 + k0;
        float4 s0 = *(const float4*)sp;
        float4 s1 = *(const float4*)(sp + 4);
        const short8 bv = *(const short8*)(bbf + (long)prow * 64 + k0);
        const short8 cv = *(const short8*)(cbf + (long)prow * 64 + k0);
        float sv[8] = {s0.x, s0.y, s0.z, s0.w, s1.x, s1.y, s1.z, s1.w};
        short8 pv;
        #pragma unroll
        for (int j = 0; j < 8; ++j) {
            float v = sv[j] - deg * b2f((unsigned short)bv[j]) + b2f((unsigned short)cv[j]);
            pv[j] = (short)f2b(v);
        }
        p[s] = pv;
    }

    const short8* wp = (const short8*)Wp;
    #pragma unroll
    for (int ct = 0; ct < 4; ++ct) {
        f32x4 z = {0.f, 0.f, 0.f, 0.f};
        short8 w0 = wp[((12 + ct) * 2 + 0) * 64 + lane];
        short8 w1 = wp[((12 + ct) * 2 + 1) * 64 + lane];
        z = __builtin_amdgcn_mfma_f32_16x16x32_bf16(p[0], w0, z, 0, 0, 0);
        z = __builtin_amdgcn_mfma_f32_16x16x32_bf16(p[1], w1, z, 0, 0, 0);
        int col = ct * 16 + lm;
        float bias = bl[col];
        #pragma unroll
        for (int r = 0; r < 4; ++r) {
            int g = row_base + quad * 4 + r;
            if (g < n) {
                float v = fmaxf(z[r] + bias, 0.0f);
                if (last) out_f[(long)g * 64 + col] = v;
                else      out_b[(long)g * 64 + col] = f2b(v);
            }
        }
    }
}

// ---------------------------------------------------------------------------
extern "C" void kernel_launch(void* const* d_in, const int* in_sizes, int n_in,
                              void* d_out, int out_size, void* d_ws, size_t ws_size,
                              hipStream_t stream) {
    const float* x  = (const float*)d_in[0];
    const int*   ei = (const int*)d_in[1];
    const int*   src = ei;
    const int*   dst = ei + N_EDGES;

    char* wsb = (char*)d_ws;
    float*          S    = (float*)(wsb);                       // 12.8 MB
    unsigned short* abf  = (unsigned short*)(wsb + 12800000);   // 6.4 MB
    unsigned short* bbf  = (unsigned short*)(wsb + 19200000);   // 6.4 MB
    unsigned short* cbf  = (unsigned short*)(wsb + 25600000);   // 6.4 MB
    unsigned short* h0   = (unsigned short*)(wsb + 32000000);   // 6.4 MB
    unsigned short* h1   = (unsigned short*)(wsb + 38400000);   // 6.4 MB
    unsigned short* Wp   = (unsigned short*)(wsb + 44800000);   // 3 * 32 KB
    int* hist_part = (int*)(wsb + 44900000);                    // 32*50000*4 = 6.4 MB
    int* cnt  = hist_part + NCHUNK * N_NODES;                   // N_NODES
    int* off  = cnt + N_NODES;                                  // N_NODES + 1
    int* bsum = off + N_NODES + 1;
    int* boff = bsum + SCAN_NB;
    int* csr  = boff + SCAN_NB;                                 // N_EDGES

    const int NBLK = (N_NODES + 63) / 64;    // 782

    // ---- CSR build: zero global atomics ----
    histp_kernel<<<NCHUNK * NRANGE, 256, 0, stream>>>(dst, hist_part);
    chunkscan_kernel<<<SCAN_NB, 256, 0, stream>>>(hist_part, cnt);
    scanA_kernel<<<SCAN_NB, 256, 0, stream>>>(cnt, off, bsum);
    scanB_kernel<<<1, 256, 0, stream>>>(bsum, boff, off);
    scanC_kernel<<<SCAN_NB, 256, 0, stream>>>(boff, off);
    fillp_kernel<<<NCHUNK * NRANGE, 256, 0, stream>>>(src, dst, off, hist_part, csr);

    // ---- bf16 conversions / weight packing ----
    convert_x_kernel<<<(N_NODES * 64 / 4 + 255) / 256, 256, 0, stream>>>(x, h0);
    for (int l = 0; l < 3; ++l) {
        int base = 2 + l * 7;
        pack_w_kernel<<<1, 256, 0, stream>>>(
            (const float*)d_in[base + 0], (const float*)d_in[base + 2],
            (const float*)d_in[base + 3], (const float*)d_in[base + 5],
            Wp + l * 16384);
    }

    const unsigned short* hin = h0;
    for (int l = 0; l < 3; ++l) {
        int base = 2 + l * 7;
        const float* b1 = (const float*)d_in[base + 1];
        const float* b3 = (const float*)d_in[base + 4];
        const float* bl = (const float*)d_in[base + 6];
        const unsigned short* wp = Wp + l * 16384;

        gemm3_mfma_kernel<<<NBLK, 256, 0, stream>>>(hin, wp, b1, b3,
                                                    abf, bbf, cbf, N_NODES);

        gather_kernel<<<(N_NODES + 3) / 4, 256, 0, stream>>>(off, csr, abf, S, N_NODES);

        int last = (l == 2);
        combine_mfma_kernel<<<NBLK, 256, 0, stream>>>(
            S, bbf, cbf, off, wp, bl,
            (float*)d_out, h1, N_NODES, last);
        hin = h1;
    }
}

// Round 6
// 360.079 us; speedup vs baseline: 1.1295x; 1.1295x over previous
//
#include <hip/hip_runtime.h>

#define N_NODES 50000
#define N_EDGES 800000
#define SCAN_NB ((N_NODES + 255) / 256)   // 196
#define NCHUNK 128
#define NRANGE 4
#define RNODES (N_NODES / NRANGE)         // 12500
#define CEDGES (N_EDGES / NCHUNK)         // 6250

typedef __attribute__((ext_vector_type(8))) short short8;
typedef __attribute__((ext_vector_type(4))) float f32x4;

__device__ inline unsigned short f2b(float f) {
    union { float f; unsigned u; } c; c.f = f;
    return (unsigned short)((c.u + 0x7FFFu + ((c.u >> 16) & 1u)) >> 16);
}
__device__ inline float b2f(unsigned short h) {
    union { unsigned u; float f; } c; c.u = ((unsigned)h) << 16;
    return c.f;
}

// ---------------------------------------------------------------------------
// K1: partial histograms (u16). Block = (chunk, range). LDS atomics only.
__global__ __launch_bounds__(256) void histp_kernel(const int* __restrict__ dst,
                                                    unsigned short* __restrict__ hist_part) {
    __shared__ int h[RNODES];
    const int chunk = blockIdx.x >> 2;
    const int range = blockIdx.x & 3;
    const int nbase = range * RNODES;
    for (int i = threadIdx.x; i < RNODES; i += 256) h[i] = 0;
    __syncthreads();
    const int* dp = dst + chunk * CEDGES;
    for (int i = threadIdx.x; i < CEDGES; i += 256) {
        int d = dp[i] - nbase;
        if ((unsigned)d < (unsigned)RNODES) atomicAdd(&h[d], 1);
    }
    __syncthreads();
    unsigned short* out = hist_part + (long)chunk * N_NODES + nbase;
    for (int i = threadIdx.x; i < RNODES; i += 256) out[i] = (unsigned short)h[i];
}

// ---------------------------------------------------------------------------
// K2: per node, exclusive scan across chunks (in place, u16) + total count.
__global__ __launch_bounds__(256) void chunkscan_kernel(unsigned short* __restrict__ hist_part,
                                                        int* __restrict__ cnt) {
    int node = blockIdx.x * 256 + threadIdx.x;
    if (node >= N_NODES) return;
    int run = 0;
    #pragma unroll
    for (int c = 0; c < NCHUNK; ++c) {
        unsigned short* p = hist_part + (long)c * N_NODES + node;
        int v = *p;
        *p = (unsigned short)run;
        run += v;
    }
    cnt[node] = run;
}

// ---------------------------------------------------------------------------
// Hierarchical scan of cnt -> off (exclusive), off[N] = total.
__global__ __launch_bounds__(256) void scanA_kernel(const int* __restrict__ cnt,
                                                    int* __restrict__ off,
                                                    int* __restrict__ bsum) {
    __shared__ int tmp[256];
    const int t = threadIdx.x;
    const int i = blockIdx.x * 256 + t;
    int v = (i < N_NODES) ? cnt[i] : 0;
    tmp[t] = v;
    __syncthreads();
    #pragma unroll
    for (int d = 1; d < 256; d <<= 1) {
        int u = (t >= d) ? tmp[t - d] : 0;
        __syncthreads();
        tmp[t] += u;
        __syncthreads();
    }
    if (i < N_NODES) off[i] = tmp[t] - v;
    if (t == 255) bsum[blockIdx.x] = tmp[255];
}

__global__ __launch_bounds__(256) void scanB_kernel(const int* __restrict__ bsum,
                                                    int* __restrict__ boff,
                                                    int* __restrict__ off) {
    __shared__ int tmp[256];
    const int t = threadIdx.x;
    int v = (t < SCAN_NB) ? bsum[t] : 0;
    tmp[t] = v;
    __syncthreads();
    #pragma unroll
    for (int d = 1; d < 256; d <<= 1) {
        int u = (t >= d) ? tmp[t - d] : 0;
        __syncthreads();
        tmp[t] += u;
        __syncthreads();
    }
    if (t < SCAN_NB) boff[t] = tmp[t] - v;
    if (t == 255) off[N_NODES] = tmp[255];
}

__global__ __launch_bounds__(256) void scanC_kernel(const int* __restrict__ boff,
                                                    int* __restrict__ off) {
    int i = blockIdx.x * 256 + threadIdx.x;
    if (i < N_NODES) off[i] += boff[blockIdx.x];
}

// ---------------------------------------------------------------------------
// K3: fill csr. Cursor = off[d] + base[chunk][d] in LDS; LDS atomics rank
// edges; plain global stores only (L2-absorbed).
__global__ __launch_bounds__(256) void fillp_kernel(const int* __restrict__ src,
                                                    const int* __restrict__ dst,
                                                    const int* __restrict__ off,
                                                    const unsigned short* __restrict__ hist_part,
                                                    int* __restrict__ csr) {
    __shared__ int cur[RNODES];
    const int chunk = blockIdx.x >> 2;
    const int range = blockIdx.x & 3;
    const int nbase = range * RNODES;
    const unsigned short* bp = hist_part + (long)chunk * N_NODES + nbase;
    const int* op = off + nbase;
    for (int i = threadIdx.x; i < RNODES; i += 256) cur[i] = op[i] + (int)bp[i];
    __syncthreads();
    const int* dp = dst + chunk * CEDGES;
    const int* sp = src + chunk * CEDGES;
    for (int i = threadIdx.x; i < CEDGES; i += 256) {
        int d = dp[i] - nbase;
        if ((unsigned)d < (unsigned)RNODES) {
            int pos = atomicAdd(&cur[d], 1);
            csr[pos] = sp[i];
        }
    }
}

// ---------------------------------------------------------------------------
// x (fp32) -> bf16
__global__ __launch_bounds__(256) void convert_x_kernel(const float* __restrict__ x,
                                                        unsigned short* __restrict__ xb) {
    long i = ((long)blockIdx.x * 256 + threadIdx.x) * 4;
    if (i < (long)N_NODES * 64) {
        float4 v = *(const float4*)(x + i);
        ushort4 o;
        o.x = f2b(v.x); o.y = f2b(v.y); o.z = f2b(v.z); o.w = f2b(v.w);
        *(ushort4*)(xb + i) = o;
    }
}

// ---------------------------------------------------------------------------
// Pack one layer's weights into B-fragment order (bf16).
__global__ __launch_bounds__(256) void pack_w_kernel(
    const float* __restrict__ W1, const float* __restrict__ W2,
    const float* __restrict__ W3, const float* __restrict__ Wl,
    unsigned short* __restrict__ Wp)
{
    for (int idx = threadIdx.x; idx < 16 * 2 * 64 * 8; idx += 256) {
        int j = idx & 7, lane = (idx >> 3) & 63, s = (idx >> 9) & 1, ct = idx >> 10;
        int k = s * 32 + (lane >> 4) * 8 + j;
        int col = ct * 16 + (lane & 15);
        float v;
        if (ct < 4)       v = W1[k * 64 + col];
        else if (ct < 8)  v = W2[k * 64 + col - 64];
        else if (ct < 12) v = W3[k * 64 + col - 128];
        else              v = Wl[k * 64 + col - 192];
        Wp[idx] = f2b(v);
    }
}

// ---------------------------------------------------------------------------
// [a|b|c] = h @ [W1|W2|W3] + [b1|0|b3], bf16 MFMA, no LDS.
__global__ __launch_bounds__(256) void gemm3_mfma_kernel(
    const unsigned short* __restrict__ hbf,
    const unsigned short* __restrict__ Wp,
    const float* __restrict__ b1, const float* __restrict__ b3,
    unsigned short* __restrict__ abf, unsigned short* __restrict__ bbf,
    unsigned short* __restrict__ cbf, int n)
{
    const int t = threadIdx.x;
    const int lane = t & 63;
    const int quad = lane >> 4, lm = lane & 15;
    const int row_base = blockIdx.x * 64 + (t >> 6) * 16;

    int arow = min(row_base + lm, n - 1);
    const unsigned short* hrow = hbf + (long)arow * 64;
    short8 a0 = *(const short8*)(hrow + quad * 8);
    short8 a1 = *(const short8*)(hrow + 32 + quad * 8);

    const short8* wp = (const short8*)Wp;
    f32x4 acc[12];
    #pragma unroll
    for (int ct = 0; ct < 12; ++ct) {
        f32x4 z = {0.f, 0.f, 0.f, 0.f};
        short8 w0 = wp[(ct * 2 + 0) * 64 + lane];
        short8 w1 = wp[(ct * 2 + 1) * 64 + lane];
        z = __builtin_amdgcn_mfma_f32_16x16x32_bf16(a0, w0, z, 0, 0, 0);
        z = __builtin_amdgcn_mfma_f32_16x16x32_bf16(a1, w1, z, 0, 0, 0);
        acc[ct] = z;
    }

    #pragma unroll
    for (int ct = 0; ct < 12; ++ct) {
        int col = ct * 16 + lm;
        float bias = 0.f;
        unsigned short* dstp;
        int lcol;
        if (ct < 4)       { bias = b1[col];        dstp = abf; lcol = col; }
        else if (ct < 8)  {                        dstp = bbf; lcol = col - 64; }
        else              { bias = b3[col - 128];  dstp = cbf; lcol = col - 128; }
        #pragma unroll
        for (int r = 0; r < 4; ++r) {
            int g = row_base + quad * 4 + r;
            if (g < n) dstp[(long)g * 64 + lcol] = f2b(acc[ct][r] + bias);
        }
    }
}

// ---------------------------------------------------------------------------
// CSR gather over bf16 a-rows.
__global__ __launch_bounds__(256) void gather_kernel(
    const int* __restrict__ off, const int* __restrict__ csr,
    const unsigned short* __restrict__ abf, float* __restrict__ S, int n)
{
    int node = blockIdx.x * 4 + (threadIdx.x >> 6);
    int lane = threadIdx.x & 63;
    if (node >= n) return;
    int beg = off[node], end = off[node + 1];
    float acc = 0.0f;
    int j = beg;
    for (; j + 3 < end; j += 4) {
        int s0 = csr[j], s1 = csr[j + 1], s2 = csr[j + 2], s3 = csr[j + 3];
        float v0 = b2f(abf[(long)s0 * 64 + lane]);
        float v1 = b2f(abf[(long)s1 * 64 + lane]);
        float v2 = b2f(abf[(long)s2 * 64 + lane]);
        float v3 = b2f(abf[(long)s3 * 64 + lane]);
        acc += v0 + v1 + v2 + v3;
    }
    for (; j < end; ++j) acc += b2f(abf[(long)csr[j] * 64 + lane]);
    S[(long)node * 64 + lane] = acc;
}

// ---------------------------------------------------------------------------
// out = relu( (S - deg*b + c) @ Wl + bl )
__global__ __launch_bounds__(256) void combine_mfma_kernel(
    const float* __restrict__ S, const unsigned short* __restrict__ bbf,
    const unsigned short* __restrict__ cbf, const int* __restrict__ off,
    const unsigned short* __restrict__ Wp, const float* __restrict__ bl,
    float* __restrict__ out_f, unsigned short* __restrict__ out_b,
    int n, int last)
{
    const int t = threadIdx.x;
    const int lane = t & 63;
    const int quad = lane >> 4, lm = lane & 15;
    const int row_base = blockIdx.x * 64 + (t >> 6) * 16;

    int prow = min(row_base + lm, n - 1);
    float deg = (float)(off[prow + 1] - off[prow]);

    short8 p[2];
    #pragma unroll
    for (int s = 0; s < 2; ++s) {
        int k0 = s * 32 + quad * 8;
        const float* sp = S + (long)prow * 64 + k0;
        float4 s0 = *(const float4*)sp;
        float4 s1 = *(const float4*)(sp + 4);
        const short8 bv = *(const short8*)(bbf + (long)prow * 64 + k0);
        const short8 cv = *(const short8*)(cbf + (long)prow * 64 + k0);
        float sv[8] = {s0.x, s0.y, s0.z, s0.w, s1.x, s1.y, s1.z, s1.w};
        short8 pv;
        #pragma unroll
        for (int j = 0; j < 8; ++j) {
            float v = sv[j] - deg * b2f((unsigned short)bv[j]) + b2f((unsigned short)cv[j]);
            pv[j] = (short)f2b(v);
        }
        p[s] = pv;
    }

    const short8* wp = (const short8*)Wp;
    #pragma unroll
    for (int ct = 0; ct < 4; ++ct) {
        f32x4 z = {0.f, 0.f, 0.f, 0.f};
        short8 w0 = wp[((12 + ct) * 2 + 0) * 64 + lane];
        short8 w1 = wp[((12 + ct) * 2 + 1) * 64 + lane];
        z = __builtin_amdgcn_mfma_f32_16x16x32_bf16(p[0], w0, z, 0, 0, 0);
        z = __builtin_amdgcn_mfma_f32_16x16x32_bf16(p[1], w1, z, 0, 0, 0);
        int col = ct * 16 + lm;
        float bias = bl[col];
        #pragma unroll
        for (int r = 0; r < 4; ++r) {
            int g = row_base + quad * 4 + r;
            if (g < n) {
                float v = fmaxf(z[r] + bias, 0.0f);
                if (last) out_f[(long)g * 64 + col] = v;
                else      out_b[(long)g * 64 + col] = f2b(v);
            }
        }
    }
}

// ---------------------------------------------------------------------------
extern "C" void kernel_launch(void* const* d_in, const int* in_sizes, int n_in,
                              void* d_out, int out_size, void* d_ws, size_t ws_size,
                              hipStream_t stream) {
    const float* x  = (const float*)d_in[0];
    const int*   ei = (const int*)d_in[1];
    const int*   src = ei;
    const int*   dst = ei + N_EDGES;

    char* wsb = (char*)d_ws;
    // hist_part (12.8 MB, u16) aliases S (12.8 MB fp32): CSR build finishes
    // before the first gather writes S, so lifetimes are disjoint.
    float*          S    = (float*)(wsb);                       // 12.8 MB
    unsigned short* hist_part = (unsigned short*)(wsb);         // 12.8 MB (aliased)
    unsigned short* abf  = (unsigned short*)(wsb + 12800000);   // 6.4 MB
    unsigned short* bbf  = (unsigned short*)(wsb + 19200000);   // 6.4 MB
    unsigned short* cbf  = (unsigned short*)(wsb + 25600000);   // 6.4 MB
    unsigned short* h0   = (unsigned short*)(wsb + 32000000);   // 6.4 MB
    unsigned short* h1   = (unsigned short*)(wsb + 38400000);   // 6.4 MB
    unsigned short* Wp   = (unsigned short*)(wsb + 44800000);   // 3 * 32 KB
    int* cnt  = (int*)(wsb + 44900000);                         // N_NODES
    int* off  = cnt + N_NODES;                                  // N_NODES + 1
    int* bsum = off + N_NODES + 1;
    int* boff = bsum + SCAN_NB;
    int* csr  = boff + SCAN_NB;                                 // N_EDGES

    const int NBLK = (N_NODES + 63) / 64;    // 782

    // ---- CSR build: zero global atomics, 512-block grids ----
    histp_kernel<<<NCHUNK * NRANGE, 256, 0, stream>>>(dst, hist_part);
    chunkscan_kernel<<<SCAN_NB, 256, 0, stream>>>(hist_part, cnt);
    scanA_kernel<<<SCAN_NB, 256, 0, stream>>>(cnt, off, bsum);
    scanB_kernel<<<1, 256, 0, stream>>>(bsum, boff, off);
    scanC_kernel<<<SCAN_NB, 256, 0, stream>>>(boff, off);
    fillp_kernel<<<NCHUNK * NRANGE, 256, 0, stream>>>(src, dst, off, hist_part, csr);

    // ---- bf16 conversions / weight packing ----
    convert_x_kernel<<<(N_NODES * 64 / 4 + 255) / 256, 256, 0, stream>>>(x, h0);
    for (int l = 0; l < 3; ++l) {
        int base = 2 + l * 7;
        pack_w_kernel<<<1, 256, 0, stream>>>(
            (const float*)d_in[base + 0], (const float*)d_in[base + 2],
            (const float*)d_in[base + 3], (const float*)d_in[base + 5],
            Wp + l * 16384);
    }

    const unsigned short* hin = h0;
    for (int l = 0; l < 3; ++l) {
        int base = 2 + l * 7;
        const float* b1 = (const float*)d_in[base + 1];
        const float* b3 = (const float*)d_in[base + 4];
        const float* bl = (const float*)d_in[base + 6];
        const unsigned short* wp = Wp + l * 16384;

        gemm3_mfma_kernel<<<NBLK, 256, 0, stream>>>(hin, wp, b1, b3,
                                                    abf, bbf, cbf, N_NODES);

        gather_kernel<<<(N_NODES + 3) / 4, 256, 0, stream>>>(off, csr, abf, S, N_NODES);

        int last = (l == 2);
        combine_mfma_kernel<<<NBLK, 256, 0, stream>>>(
            S, bbf, cbf, off, wp, bl,
            (float*)d_out, h1, N_NODES, last);
        hin = h1;
    }
}

// Round 7
// 302.459 us; speedup vs baseline: 1.3447x; 1.1905x over previous
//
#include <hip/hip_runtime.h>

#define N_NODES 50000
#define N_EDGES 800000
#define SCAN_NB ((N_NODES + 255) / 256)   // 196
#define NCHUNK 128
#define NRANGE 4
#define RNODES (N_NODES / NRANGE)         // 12500
#define CEDGES (N_EDGES / NCHUNK)         // 6250

typedef __attribute__((ext_vector_type(8))) short short8;
typedef __attribute__((ext_vector_type(4))) float f32x4;

struct WPtrs { const float* p[12]; };

__device__ inline unsigned short f2b(float f) {
    union { float f; unsigned u; } c; c.f = f;
    return (unsigned short)((c.u + 0x7FFFu + ((c.u >> 16) & 1u)) >> 16);
}
__device__ inline float b2f(unsigned short h) {
    union { unsigned u; float f; } c; c.u = ((unsigned)h) << 16;
    return c.f;
}

// ---------------------------------------------------------------------------
// K1: partial histograms (u16). Block = (chunk, range). LDS atomics only.
__global__ __launch_bounds__(256) void histp_kernel(const int* __restrict__ dst,
                                                    unsigned short* __restrict__ hist_part) {
    __shared__ int h[RNODES];
    const int chunk = blockIdx.x >> 2;
    const int range = blockIdx.x & 3;
    const int nbase = range * RNODES;
    for (int i = threadIdx.x; i < RNODES; i += 256) h[i] = 0;
    __syncthreads();
    const int* dp = dst + chunk * CEDGES;
    for (int i = threadIdx.x; i < CEDGES; i += 256) {
        int d = dp[i] - nbase;
        if ((unsigned)d < (unsigned)RNODES) atomicAdd(&h[d], 1);
    }
    __syncthreads();
    unsigned short* out = hist_part + (long)chunk * N_NODES + nbase;
    for (int i = threadIdx.x; i < RNODES; i += 256) out[i] = (unsigned short)h[i];
}

// ---------------------------------------------------------------------------
// K2: per node, exclusive scan across chunks (in place, u16) + total count.
__global__ __launch_bounds__(256) void chunkscan_kernel(unsigned short* __restrict__ hist_part,
                                                        int* __restrict__ cnt) {
    int node = blockIdx.x * 256 + threadIdx.x;
    if (node >= N_NODES) return;
    int run = 0;
    #pragma unroll
    for (int c = 0; c < NCHUNK; ++c) {
        unsigned short* p = hist_part + (long)c * N_NODES + node;
        int v = *p;
        *p = (unsigned short)run;
        run += v;
    }
    cnt[node] = run;
}

// ---------------------------------------------------------------------------
// Hierarchical scan of cnt -> off (exclusive), off[N] = total.
__global__ __launch_bounds__(256) void scanA_kernel(const int* __restrict__ cnt,
                                                    int* __restrict__ off,
                                                    int* __restrict__ bsum) {
    __shared__ int tmp[256];
    const int t = threadIdx.x;
    const int i = blockIdx.x * 256 + t;
    int v = (i < N_NODES) ? cnt[i] : 0;
    tmp[t] = v;
    __syncthreads();
    #pragma unroll
    for (int d = 1; d < 256; d <<= 1) {
        int u = (t >= d) ? tmp[t - d] : 0;
        __syncthreads();
        tmp[t] += u;
        __syncthreads();
    }
    if (i < N_NODES) off[i] = tmp[t] - v;
    if (t == 255) bsum[blockIdx.x] = tmp[255];
}

__global__ __launch_bounds__(256) void scanB_kernel(const int* __restrict__ bsum,
                                                    int* __restrict__ boff,
                                                    int* __restrict__ off) {
    __shared__ int tmp[256];
    const int t = threadIdx.x;
    int v = (t < SCAN_NB) ? bsum[t] : 0;
    tmp[t] = v;
    __syncthreads();
    #pragma unroll
    for (int d = 1; d < 256; d <<= 1) {
        int u = (t >= d) ? tmp[t - d] : 0;
        __syncthreads();
        tmp[t] += u;
        __syncthreads();
    }
    if (t < SCAN_NB) boff[t] = tmp[t] - v;
    if (t == 255) off[N_NODES] = tmp[255];
}

__global__ __launch_bounds__(256) void scanC_kernel(const int* __restrict__ boff,
                                                    int* __restrict__ off) {
    int i = blockIdx.x * 256 + threadIdx.x;
    if (i < N_NODES) off[i] += boff[blockIdx.x];
}

// ---------------------------------------------------------------------------
// K3: fill csr. Cursor = off[d] + base[chunk][d] in LDS; LDS atomics rank
// edges; plain global stores only (L2-absorbed).
__global__ __launch_bounds__(256) void fillp_kernel(const int* __restrict__ src,
                                                    const int* __restrict__ dst,
                                                    const int* __restrict__ off,
                                                    const unsigned short* __restrict__ hist_part,
                                                    int* __restrict__ csr) {
    __shared__ int cur[RNODES];
    const int chunk = blockIdx.x >> 2;
    const int range = blockIdx.x & 3;
    const int nbase = range * RNODES;
    const unsigned short* bp = hist_part + (long)chunk * N_NODES + nbase;
    const int* op = off + nbase;
    for (int i = threadIdx.x; i < RNODES; i += 256) cur[i] = op[i] + (int)bp[i];
    __syncthreads();
    const int* dp = dst + chunk * CEDGES;
    const int* sp = src + chunk * CEDGES;
    for (int i = threadIdx.x; i < CEDGES; i += 256) {
        int d = dp[i] - nbase;
        if ((unsigned)d < (unsigned)RNODES) {
            int pos = atomicAdd(&cur[d], 1);
            csr[pos] = sp[i];
        }
    }
}

// ---------------------------------------------------------------------------
// Pack ALL layers' weights into B-fragment order (bf16). Grid = 3*16 blocks.
__global__ __launch_bounds__(256) void pack_w_all_kernel(WPtrs wp,
                                                         unsigned short* __restrict__ Wp)
{
    const int layer = blockIdx.x >> 4;
    const int ct = blockIdx.x & 15;
    const float* W = wp.p[layer * 4 + (ct >> 2)];
    const int colb = (ct & 3) * 16;
    for (int local = threadIdx.x; local < 1024; local += 256) {
        int j = local & 7, lane = (local >> 3) & 63, s = local >> 9;
        int k = s * 32 + (lane >> 4) * 8 + j;
        int col = colb + (lane & 15);
        Wp[layer * 16384 + ct * 1024 + local] = f2b(W[k * 64 + col]);
    }
}

// ---------------------------------------------------------------------------
// [a|b|c] = h @ [W1|W2|W3] + [b1|0|b3], bf16 MFMA, no LDS.
// hf32 != null (layer 0): read fp32 x, cast in-register.
__global__ __launch_bounds__(256) void gemm3_mfma_kernel(
    const unsigned short* __restrict__ hbf, const float* __restrict__ hf32,
    const unsigned short* __restrict__ Wp,
    const float* __restrict__ b1, const float* __restrict__ b3,
    unsigned short* __restrict__ abf, unsigned short* __restrict__ bbf,
    unsigned short* __restrict__ cbf, int n)
{
    const int t = threadIdx.x;
    const int lane = t & 63;
    const int quad = lane >> 4, lm = lane & 15;
    const int row_base = blockIdx.x * 64 + (t >> 6) * 16;

    int arow = min(row_base + lm, n - 1);
    short8 a0, a1;
    if (hf32) {
        const float* hrow = hf32 + (long)arow * 64;
        #pragma unroll
        for (int j = 0; j < 8; ++j) {
            a0[j] = (short)f2b(hrow[quad * 8 + j]);
            a1[j] = (short)f2b(hrow[32 + quad * 8 + j]);
        }
    } else {
        const unsigned short* hrow = hbf + (long)arow * 64;
        a0 = *(const short8*)(hrow + quad * 8);
        a1 = *(const short8*)(hrow + 32 + quad * 8);
    }

    const short8* wp = (const short8*)Wp;
    f32x4 acc[12];
    #pragma unroll
    for (int ct = 0; ct < 12; ++ct) {
        f32x4 z = {0.f, 0.f, 0.f, 0.f};
        short8 w0 = wp[(ct * 2 + 0) * 64 + lane];
        short8 w1 = wp[(ct * 2 + 1) * 64 + lane];
        z = __builtin_amdgcn_mfma_f32_16x16x32_bf16(a0, w0, z, 0, 0, 0);
        z = __builtin_amdgcn_mfma_f32_16x16x32_bf16(a1, w1, z, 0, 0, 0);
        acc[ct] = z;
    }

    #pragma unroll
    for (int ct = 0; ct < 12; ++ct) {
        int col = ct * 16 + lm;
        float bias = 0.f;
        unsigned short* dstp;
        int lcol;
        if (ct < 4)       { bias = b1[col];        dstp = abf; lcol = col; }
        else if (ct < 8)  {                        dstp = bbf; lcol = col - 64; }
        else              { bias = b3[col - 128];  dstp = cbf; lcol = col - 128; }
        #pragma unroll
        for (int r = 0; r < 4; ++r) {
            int g = row_base + quad * 4 + r;
            if (g < n) dstp[(long)g * 64 + lcol] = f2b(acc[ct][r] + bias);
        }
    }
}

// ---------------------------------------------------------------------------
// CSR gather, vectorized: wave = 1 node; lane -> (edge group g=lane>>4,
// feature quad f=(lane&15)*4). Each load instr covers 4 edges x ushort4 =
// 512 B. Cross-group reduce via 2 xor-shuffle rounds.
__global__ __launch_bounds__(256) void gather_kernel(
    const int* __restrict__ off, const int* __restrict__ csr,
    const unsigned short* __restrict__ abf, float* __restrict__ S, int n)
{
    int node = blockIdx.x * 4 + (threadIdx.x >> 6);
    int lane = threadIdx.x & 63;
    if (node >= n) return;
    const int g = lane >> 4;
    const int f = (lane & 15) * 4;
    int beg = off[node], end = off[node + 1];
    float ax = 0.f, ay = 0.f, az = 0.f, aw = 0.f;
    int j = beg;
    // guard-free main loop: 8 edges / iter, 2 loads in flight
    for (; j + 8 <= end; j += 8) {
        int s0 = csr[j + g], s1 = csr[j + 4 + g];
        ushort4 v0 = *(const ushort4*)(abf + (long)s0 * 64 + f);
        ushort4 v1 = *(const ushort4*)(abf + (long)s1 * 64 + f);
        ax += b2f(v0.x) + b2f(v1.x);
        ay += b2f(v0.y) + b2f(v1.y);
        az += b2f(v0.z) + b2f(v1.z);
        aw += b2f(v0.w) + b2f(v1.w);
    }
    for (; j < end; j += 4) {
        int jj = j + g;
        if (jj < end) {
            int s0 = csr[jj];
            ushort4 v0 = *(const ushort4*)(abf + (long)s0 * 64 + f);
            ax += b2f(v0.x); ay += b2f(v0.y); az += b2f(v0.z); aw += b2f(v0.w);
        }
    }
    #pragma unroll
    for (int m = 16; m < 64; m <<= 1) {
        ax += __shfl_xor(ax, m, 64);
        ay += __shfl_xor(ay, m, 64);
        az += __shfl_xor(az, m, 64);
        aw += __shfl_xor(aw, m, 64);
    }
    if (g == 0) {
        float4 o = {ax, ay, az, aw};
        *(float4*)(S + (long)node * 64 + f) = o;
    }
}

// ---------------------------------------------------------------------------
// out = relu( (S - deg*b + c) @ Wl + bl )
__global__ __launch_bounds__(256) void combine_mfma_kernel(
    const float* __restrict__ S, const unsigned short* __restrict__ bbf,
    const unsigned short* __restrict__ cbf, const int* __restrict__ off,
    const unsigned short* __restrict__ Wp, const float* __restrict__ bl,
    float* __restrict__ out_f, unsigned short* __restrict__ out_b,
    int n, int last)
{
    const int t = threadIdx.x;
    const int lane = t & 63;
    const int quad = lane >> 4, lm = lane & 15;
    const int row_base = blockIdx.x * 64 + (t >> 6) * 16;

    int prow = min(row_base + lm, n - 1);
    float deg = (float)(off[prow + 1] - off[prow]);

    short8 p[2];
    #pragma unroll
    for (int s = 0; s < 2; ++s) {
        int k0 = s * 32 + quad * 8;
        const float* sp = S + (long)prow * 64 + k0;
        float4 s0 = *(const float4*)sp;
        float4 s1 = *(const float4*)(sp + 4);
        const short8 bv = *(const short8*)(bbf + (long)prow * 64 + k0);
        const short8 cv = *(const short8*)(cbf + (long)prow * 64 + k0);
        float sv[8] = {s0.x, s0.y, s0.z, s0.w, s1.x, s1.y, s1.z, s1.w};
        short8 pv;
        #pragma unroll
        for (int j = 0; j < 8; ++j) {
            float v = sv[j] - deg * b2f((unsigned short)bv[j]) + b2f((unsigned short)cv[j]);
            pv[j] = (short)f2b(v);
        }
        p[s] = pv;
    }

    const short8* wp = (const short8*)Wp;
    #pragma unroll
    for (int ct = 0; ct < 4; ++ct) {
        f32x4 z = {0.f, 0.f, 0.f, 0.f};
        short8 w0 = wp[((12 + ct) * 2 + 0) * 64 + lane];
        short8 w1 = wp[((12 + ct) * 2 + 1) * 64 + lane];
        z = __builtin_amdgcn_mfma_f32_16x16x32_bf16(p[0], w0, z, 0, 0, 0);
        z = __builtin_amdgcn_mfma_f32_16x16x32_bf16(p[1], w1, z, 0, 0, 0);
        int col = ct * 16 + lm;
        float bias = bl[col];
        #pragma unroll
        for (int r = 0; r < 4; ++r) {
            int g = row_base + quad * 4 + r;
            if (g < n) {
                float v = fmaxf(z[r] + bias, 0.0f);
                if (last) out_f[(long)g * 64 + col] = v;
                else      out_b[(long)g * 64 + col] = f2b(v);
            }
        }
    }
}

// ---------------------------------------------------------------------------
extern "C" void kernel_launch(void* const* d_in, const int* in_sizes, int n_in,
                              void* d_out, int out_size, void* d_ws, size_t ws_size,
                              hipStream_t stream) {
    const float* x  = (const float*)d_in[0];
    const int*   ei = (const int*)d_in[1];
    const int*   src = ei;
    const int*   dst = ei + N_EDGES;

    char* wsb = (char*)d_ws;
    // hist_part (12.8 MB, u16) aliases S (12.8 MB fp32): lifetimes disjoint.
    float*          S    = (float*)(wsb);                       // 12.8 MB
    unsigned short* hist_part = (unsigned short*)(wsb);         // 12.8 MB (aliased)
    unsigned short* abf  = (unsigned short*)(wsb + 12800000);   // 6.4 MB
    unsigned short* bbf  = (unsigned short*)(wsb + 19200000);   // 6.4 MB
    unsigned short* cbf  = (unsigned short*)(wsb + 25600000);   // 6.4 MB
    unsigned short* h1   = (unsigned short*)(wsb + 32000000);   // 6.4 MB
    unsigned short* Wp   = (unsigned short*)(wsb + 44800000);   // 3 * 32 KB
    int* cnt  = (int*)(wsb + 44900000);                         // N_NODES
    int* off  = cnt + N_NODES;                                  // N_NODES + 1
    int* bsum = off + N_NODES + 1;
    int* boff = bsum + SCAN_NB;
    int* csr  = boff + SCAN_NB;                                 // N_EDGES

    const int NBLK = (N_NODES + 63) / 64;    // 782

    // ---- CSR build: zero global atomics ----
    histp_kernel<<<NCHUNK * NRANGE, 256, 0, stream>>>(dst, hist_part);
    chunkscan_kernel<<<SCAN_NB, 256, 0, stream>>>(hist_part, cnt);
    scanA_kernel<<<SCAN_NB, 256, 0, stream>>>(cnt, off, bsum);
    scanB_kernel<<<1, 256, 0, stream>>>(bsum, boff, off);
    scanC_kernel<<<SCAN_NB, 256, 0, stream>>>(boff, off);
    fillp_kernel<<<NCHUNK * NRANGE, 256, 0, stream>>>(src, dst, off, hist_part, csr);

    // ---- weight packing: one kernel, all layers ----
    WPtrs wps;
    for (int l = 0; l < 3; ++l) {
        int base = 2 + l * 7;
        wps.p[l * 4 + 0] = (const float*)d_in[base + 0];
        wps.p[l * 4 + 1] = (const float*)d_in[base + 2];
        wps.p[l * 4 + 2] = (const float*)d_in[base + 3];
        wps.p[l * 4 + 3] = (const float*)d_in[base + 5];
    }
    pack_w_all_kernel<<<48, 256, 0, stream>>>(wps, Wp);

    const unsigned short* hin = nullptr;   // layer 0 reads x directly
    for (int l = 0; l < 3; ++l) {
        int base = 2 + l * 7;
        const float* b1 = (const float*)d_in[base + 1];
        const float* b3 = (const float*)d_in[base + 4];
        const float* bl = (const float*)d_in[base + 6];
        const unsigned short* wp = Wp + l * 16384;

        gemm3_mfma_kernel<<<NBLK, 256, 0, stream>>>(
            hin, (l == 0) ? x : nullptr, wp, b1, b3, abf, bbf, cbf, N_NODES);

        gather_kernel<<<(N_NODES + 3) / 4, 256, 0, stream>>>(off, csr, abf, S, N_NODES);

        int last = (l == 2);
        combine_mfma_kernel<<<NBLK, 256, 0, stream>>>(
            S, bbf, cbf, off, wp, bl,
            (float*)d_out, h1, N_NODES, last);
        hin = h1;
    }
}